// Round 6
// baseline (372.633 us; speedup 1.0000x reference)
//
#include <hip/hip_runtime.h>
#include <math.h>

#define NH 16
#define NB 64
#define DK 64
#define NE 32768
#define TPB 256
#define TPF 512

typedef float vf4 __attribute__((ext_vector_type(4)));

// ---------------- K1: segment bounds from sorted batch ----------------
__global__ void seg_bounds_kernel(const int* __restrict__ batch, int* __restrict__ bounds) {
    int e = blockIdx.x * 256 + threadIdx.x;
    if (e >= NE) return;
    int be = batch[e];
    if (e == 0) {
        for (int b = 0; b <= be; ++b) bounds[b] = 0;
    } else {
        int bp = batch[e - 1];
        for (int b = bp + 1; b <= be; ++b) bounds[b] = e;
    }
    if (e == NE - 1) {
        for (int b = be + 1; b <= NB; ++b) bounds[b] = NE;
    }
}

// ---------------- K2: pure NT memset of attn [NH*NB*NE floats] ----------------
// Stream-order guarantees K4's p-writes land after these zeros.
__global__ __launch_bounds__(TPB) void attn_zero_kernel(float* __restrict__ attn) {
    vf4 z = {0.f, 0.f, 0.f, 0.f};
    vf4* a4 = (vf4*)attn;
    const size_t n4 = (size_t)NH * NB * NE / 4;
    size_t i = (size_t)blockIdx.x * TPB + threadIdx.x;
    const size_t stride = (size_t)gridDim.x * TPB;
    for (; i < n4; i += stride)
        __builtin_nontemporal_store(z, a4 + i);
}

// ---------------- K3: scores, one thread per (h,e) ----------------
// s[h,e] = Q[h, batch[e]] . K[h,e].  Pure stream: 16 independent NT K-loads,
// cached Q/batch loads, FMA tree, one coalesced store. No exp/shuffle/LDS.
__global__ __launch_bounds__(TPB) void scores_kernel(
    const float* __restrict__ Q,      // [NH, NB, DK]
    const float* __restrict__ K,      // [NH, NE, DK]
    const int*   __restrict__ batch,  // [NE]
    float* __restrict__ ksc)          // [NH, NE]
{
    const int h = blockIdx.x >> 7;                       // 128 blocks per head
    const int e = ((blockIdx.x & 127) << 8) + threadIdx.x;
    const int b = batch[e];
    const vf4* qrow = (const vf4*)(Q + ((size_t)h * NB + b) * DK);
    const vf4* krow = (const vf4*)(K + ((size_t)h * NE + e) * DK);
    float s0 = 0.f, s1 = 0.f, s2 = 0.f, s3 = 0.f;
    #pragma unroll
    for (int j = 0; j < DK / 4; ++j) {
        vf4 kv = __builtin_nontemporal_load(krow + j);
        vf4 qv = qrow[j];
        s0 = fmaf(kv.x, qv.x, s0);
        s1 = fmaf(kv.y, qv.y, s1);
        s2 = fmaf(kv.z, qv.z, s2);
        s3 = fmaf(kv.w, qv.w, s3);
    }
    ksc[(size_t)h * NE + e] = (s0 + s1) + (s2 + s3);     // cached: re-read by K4
}

// ---------------- K4: softmax + p-write + AV, one block per (h,b) ----------------
__global__ __launch_bounds__(TPF) void finalize_kernel(
    const float* __restrict__ V,        // [NH, NE, DK]
    const int*   __restrict__ bounds,   // [NB+1]
    const float* __restrict__ ksc_base, // [NH, NE]
    float* __restrict__ out,            // [NH, NB, DK]
    float* __restrict__ attn)           // [NH, NB, NE]
{
    const int b    = blockIdx.x;
    const int h    = blockIdx.y;
    const int tid  = threadIdx.x;
    const int wave = tid >> 6;
    const int lane = tid & 63;

    const int start = bounds[b];
    const int end   = bounds[b + 1];

    const float* ksc  = ksc_base + (size_t)h * NE;
    float*       arow = attn + ((size_t)h * NB + b) * NE;

    __shared__ float smax[8], ssum[8];
    __shared__ float red[8][DK];

    // --- Pass A: segment max (ksc is L2-hot, coalesced) ---
    float m = -INFINITY;
    for (int e = start + tid; e < end; e += TPF) m = fmaxf(m, ksc[e]);
    #pragma unroll
    for (int off = 32; off; off >>= 1) m = fmaxf(m, __shfl_xor(m, off));
    if (lane == 0) smax[wave] = m;
    __syncthreads();
    float M = -INFINITY;
    #pragma unroll
    for (int w = 0; w < 8; ++w) M = fmaxf(M, smax[w]);

    // --- Pass B: exp-sum ---
    float l = 0.f;
    for (int e = start + tid; e < end; e += TPF) l += __expf(ksc[e] - M);
    #pragma unroll
    for (int off = 32; off; off >>= 1) l += __shfl_xor(l, off);
    if (lane == 0) ssum[wave] = l;
    __syncthreads();
    float L = 0.f;
    #pragma unroll
    for (int w = 0; w < 8; ++w) L += ssum[w];
    const float inv = (L > 0.f) ? 1.f / L : 0.f;

    // --- Pass C: normalized p into segment region (coalesced, NT) ---
    for (int e = start + tid; e < end; e += TPF)
        __builtin_nontemporal_store(__expf(ksc[e] - M) * inv, arow + e);

    // --- Pass D: out[d] = sum_e p_e * V[e,d]; lane=d, wave-chunked, unroll 8 ---
    const int S   = end - start;
    const int per = (S + 7) >> 3;
    const int cb  = start + wave * per;
    int ce = cb + per; if (ce > end) ce = end;

    float a0=0.f,a1=0.f,a2=0.f,a3=0.f,a4=0.f,a5=0.f,a6=0.f,a7=0.f;
    int e = cb;
    for (; e + 7 < ce; e += 8) {
        float p0 = __expf(ksc[e+0] - M) * inv;
        float p1 = __expf(ksc[e+1] - M) * inv;
        float p2 = __expf(ksc[e+2] - M) * inv;
        float p3 = __expf(ksc[e+3] - M) * inv;
        float p4 = __expf(ksc[e+4] - M) * inv;
        float p5 = __expf(ksc[e+5] - M) * inv;
        float p6 = __expf(ksc[e+6] - M) * inv;
        float p7 = __expf(ksc[e+7] - M) * inv;
        const float* vb = V + ((size_t)h * NE + e) * DK + lane;
        a0 = fmaf(p0, __builtin_nontemporal_load(vb + 0*DK), a0);
        a1 = fmaf(p1, __builtin_nontemporal_load(vb + 1*DK), a1);
        a2 = fmaf(p2, __builtin_nontemporal_load(vb + 2*DK), a2);
        a3 = fmaf(p3, __builtin_nontemporal_load(vb + 3*DK), a3);
        a4 = fmaf(p4, __builtin_nontemporal_load(vb + 4*DK), a4);
        a5 = fmaf(p5, __builtin_nontemporal_load(vb + 5*DK), a5);
        a6 = fmaf(p6, __builtin_nontemporal_load(vb + 6*DK), a6);
        a7 = fmaf(p7, __builtin_nontemporal_load(vb + 7*DK), a7);
    }
    for (; e < ce; ++e) {
        float p = __expf(ksc[e] - M) * inv;
        a0 = fmaf(p, __builtin_nontemporal_load(V + ((size_t)h * NE + e) * DK + lane), a0);
    }
    red[wave][lane] = ((a0 + a1) + (a2 + a3)) + ((a4 + a5) + (a6 + a7));
    __syncthreads();
    if (wave == 0) {
        float r = 0.f;
        #pragma unroll
        for (int w = 0; w < 8; ++w) r += red[w][lane];
        out[((size_t)h * NB + b) * DK + lane] = r;
    }
}

extern "C" void kernel_launch(void* const* d_in, const int* in_sizes, int n_in,
                              void* d_out, int out_size, void* d_ws, size_t ws_size,
                              hipStream_t stream) {
    const float* Q     = (const float*)d_in[0];
    const float* K     = (const float*)d_in[1];
    const float* V     = (const float*)d_in[2];
    const int*   batch = (const int*)d_in[3];

    float* out  = (float*)d_out;                    // [NH,NB,DK]
    float* attn = out + (size_t)NH * NB * DK;       // [NH,NB,NE]

    int*   bounds = (int*)d_ws;                     // [NB+1], padded to 512 B
    float* ksc    = (float*)d_ws + 128;             // [NH,NE]

    seg_bounds_kernel<<<NE / 256, 256, 0, stream>>>(batch, bounds);
    attn_zero_kernel<<<2048, TPB, 0, stream>>>(attn);
    scores_kernel<<<NH * (NE / TPB), TPB, 0, stream>>>(Q, K, batch, ksc);
    dim3 fgrid(NB, NH);
    finalize_kernel<<<fgrid, TPF, 0, stream>>>(V, bounds, ksc, out, attn);
}